// Round 8
// baseline (4096.997 us; speedup 1.0000x reference)
//
#include <hip/hip_runtime.h>

#define BATCH  4096
#define HID    1024
#define NOUT   64
#define TSTEPS 25
#define KA2    1280   // 128 (static) + 1024 (h1) + 64 (y) + 64 zero-pad; row stride
#define KT0    1216   // L0 K-tiles cover cols 0..1215 (pad tile skipped)
#define KB     2048   // 1024 (h1) + 1024 (h2)
#define LDY    1600   // TSTEPS * NOUT

typedef __attribute__((ext_vector_type(8))) __bf16 bf16x8;
typedef __attribute__((ext_vector_type(4))) float  floatx4;

__device__ __forceinline__ unsigned short f2bf(float f) {
    union { float f; unsigned u; } v; v.f = f;
    unsigned r = v.u + 0x7fffu + ((v.u >> 16) & 1u);
    return (unsigned short)(r >> 16);
}
__device__ __forceinline__ float rcpf(float x) { return __builtin_amdgcn_rcpf(x); }
__device__ __forceinline__ float sigmf(float x) { return rcpf(1.0f + __expf(-x)); }
__device__ __forceinline__ float tanh_fast(float x) {
    float ax = fabsf(x);
    float e  = __expf(-2.0f * ax);
    float t  = (1.0f - e) * rcpf(1.0f + e);
    return copysignf(t, x);
}

#define GLDS16(gp, lp) __builtin_amdgcn_global_load_lds( \
    (const __attribute__((address_space(1))) void*)(gp), \
    (__attribute__((address_space(3))) void*)(lp), 16, 0, 0)

#define SB() __builtin_amdgcn_sched_barrier(0)

// v15 = v11 GEMM body (best-known; v14's kk-outer reverted: measured -2%)
// + FUSED out-GEMM tail phase in the L1 dispatch (wt != nullptr):
//   after the LSTM epilogue, each block release-fetch_adds cnt[bx] (emits
//   vmcnt-drain + buffer_wbl2 -> its H2f stores reach the coherence point),
//   spins RELAXED until all 16 panel blocks arrive (no L2 invalidate:
//   consumer L2 lines for H2f were invalidated at kernel start and only
//   rewritten fresh by same-XCD blocks), then computes y for its own 16
//   rows (k-ascending fp32 dot = bitwise-identical to the old out_gemm),
//   writing out[:,t,:] and bf16 y into X0n K-tail cols 1152..1215.
// Removes 25 out_gemm dispatches + their launch gaps. Co-residency of all
// 256 blocks (required by the spin) was proven by the R5 cooperative launch.
// X0 layout now [static 128 | h1 1024 | y 64 | pad 64]; L0 runs Kt=1216
// (19 tiles, pad tile skipped).
__global__ __launch_bounds__(512, 2) void lstm_gate_gemm(
    const unsigned short* __restrict__ X, int K, int Kt,
    const unsigned short* __restrict__ W,
    const float* __restrict__ ginit,
    float* __restrict__ cell,
    unsigned short* __restrict__ d1, int ld1, int off1,
    unsigned short* __restrict__ d2, int ld2, int off2,
    float* __restrict__ dfp,
    const float* __restrict__ wt, const float* __restrict__ bo,
    float* __restrict__ yout, unsigned short* __restrict__ xnY,
    unsigned* cnt)
{
    // [buf0 | buf1], each: A0 @0, A1 @16K, B0 @32K, B1 @48K (16 KB half-tiles)
    __shared__ __align__(16) char smem[131072];

    const int tid  = threadIdx.x;
    const int lane = tid & 63;
    const int w    = tid >> 6;          // 0..7
    const int ql   = lane >> 4;         // 0..3 (K-chunk group of the frag)
    const int lr   = lane & 15;
    const int wr   = w >> 2;            // 0..1: 64-row half of the quadrant's 128
    const int wc   = w & 3;             // 0..3: 32-col slice of the quadrant's 128

    // XCD-aware swizzle (8 XCDs round-robin on flat block id)
    const int id  = blockIdx.y * 16 + blockIdx.x;
    const int xcd = id & 7;
    const int c   = id >> 3;
    const int bx  = (xcd & 3) * 4 + (c & 3);
    const int by  = (xcd >> 2) * 8 + (c >> 2);
    const int m0  = bx * 256;
    const int j0  = by * 64;

    // ---- staging sources: half-tile slot s = w*128 + lane (+64 for e=1)
    // slot s holds global chunk (row = s>>3, kc = (s&7)^(row&7)).
    const int s0  = w * 128 + lane;
    const int r0  = s0 >> 3;
    const int kc0 = (s0 & 7) ^ (r0 & 7);
    const unsigned sOff = (unsigned)s0 * 16;   // LDS byte offset within region (e=1: +1024)
    const unsigned short* sA[2];
    const unsigned short* sB[2];
    sA[0] = X + (size_t)(m0 + r0) * K + kc0 * 8;
    sA[1] = X + (size_t)(m0 + 128 + r0) * K + kc0 * 8;
    {
        const int nb0 = r0, nb1 = 128 + r0;    // B rows = gate-interleaved cols
        sB[0] = W + (size_t)((nb0 & 3) * HID + j0 + (nb0 >> 2)) * K + kc0 * 8;
        sB[1] = W + (size_t)((nb1 & 3) * HID + j0 + (nb1 >> 2)) * K + kc0 * 8;
    }

#define STAGE_A(h, tt, p) do { \
    const unsigned short* _s = sA[h] + (size_t)(tt) * 64; \
    char* _d = smem + (p) + (h) * 16384 + sOff; \
    GLDS16(_s, _d); \
    GLDS16(_s + 8 * (size_t)K, _d + 1024); \
} while (0)

#define STAGE_B(h, tt, p) do { \
    const unsigned short* _s = sB[h] + (size_t)(tt) * 64; \
    char* _d = smem + (p) + 32768 + (h) * 16384 + sOff; \
    GLDS16(_s, _d); \
    GLDS16(_s + 2 * (size_t)K, _d + 1024); \
} while (0)

    // ---- fragment ds_read offsets (relative to half-tile base; kk=1 -> ^64)
    unsigned offA[4], offB[2];
#pragma unroll
    for (int fi = 0; fi < 4; ++fi) {
        int r = wr * 64 + fi * 16 + lr;
        offA[fi] = (unsigned)((r * 8 + (ql ^ (r & 7))) * 16);
    }
#pragma unroll
    for (int fj = 0; fj < 2; ++fj) {
        int r = wc * 32 + fj * 16 + lr;
        offB[fj] = (unsigned)(32768 + (r * 8 + (ql ^ (r & 7))) * 16);
    }

#define LOAD_A(AV, BASE) do { \
    const char* _ab = smem + (BASE); \
    _Pragma("unroll") \
    for (int fi = 0; fi < 4; ++fi) { \
        AV[fi][0] = *(const bf16x8*)(_ab + offA[fi]); \
        AV[fi][1] = *(const bf16x8*)(_ab + (offA[fi] ^ 64u)); \
    } \
} while (0)

#define LOAD_B(BV, BASE) do { \
    const char* _bb = smem + (BASE); \
    _Pragma("unroll") \
    for (int fj = 0; fj < 2; ++fj) { \
        BV[fj][0] = *(const bf16x8*)(_bb + offB[fj]); \
        BV[fj][1] = *(const bf16x8*)(_bb + (offB[fj] ^ 64u)); \
    } \
} while (0)

#define MFMA_PART(Q, AV, BV, F0, F1) do { \
    __builtin_amdgcn_s_setprio(1); \
    _Pragma("unroll") \
    for (int fi = (F0); fi < (F1); ++fi) \
    _Pragma("unroll") \
    for (int fj = 0; fj < 2; ++fj) \
    _Pragma("unroll") \
    for (int kk = 0; kk < 2; ++kk) \
        acc[Q][fi][fj] = __builtin_amdgcn_mfma_f32_16x16x32_bf16( \
            AV[fi][kk], BV[fj][kk], acc[Q][fi][fj], 0, 0, 0); \
    __builtin_amdgcn_s_setprio(0); \
} while (0)

    floatx4 acc[4][4][2];   // [quadrant][fi][fj]; q: 0=(A0,B0) 1=(A0,B1) 2=(A1,B1) 3=(A1,B0)
#pragma unroll
    for (int q = 0; q < 4; ++q)
#pragma unroll
        for (int i = 0; i < 4; ++i)
#pragma unroll
            for (int j = 0; j < 2; ++j)
                acc[q][i][j] = floatx4{0.f, 0.f, 0.f, 0.f};

    const int NT = Kt >> 6;   // 64-wide K-tiles (19 or 32)

    bf16x8 av0[4][2], av1[4][2], bv0[2][2], bv1[2][2];

    // ---- prologue: stage tile0 -> buf0 (oldest in FIFO), tile1 -> buf1.
    STAGE_B(1, 0, 0); STAGE_A(1, 0, 0); STAGE_A(0, 0, 0); STAGE_B(0, 0, 0);
    STAGE_B(1, 1, 65536); STAGE_A(1, 1, 65536); STAGE_A(0, 1, 65536); STAGE_B(0, 1, 65536);
    asm volatile("s_waitcnt vmcnt(8)");      // tile0's 8 loads landed; tile1 in flight
    __builtin_amdgcn_s_barrier();
    SB();
    LOAD_A(av0, 0);          // buf0.A0(0)
    LOAD_B(bv0, 0);          // buf0.B0(0)
    LOAD_B(bv1, 16384);      // buf0.B1(0)
    SB();

    int par = 0;
    for (int t = 0; t < NT; ++t) {
        const int cur = par << 16;
        const int np  = cur ^ 65536;
        const int t2  = (t + 2 < NT) ? t + 2 : NT - 1;  // clamp: keeps vmcnt uniform
        // ---- P0: Q0 (av0 x bv0) | av1 <- cur.A1(t) | stage B1(t+2)->cur
        __builtin_amdgcn_s_barrier();
        SB();
        MFMA_PART(0, av0, bv0, 0, 1);
        SB();
        LOAD_A(av1, cur + 16384);
        STAGE_B(1, t2, cur);
        SB();
        MFMA_PART(0, av0, bv0, 1, 4);
        SB();
        // ---- P1: Q1 (av0 x bv1) | stage A1(t+2)->cur
        __builtin_amdgcn_s_barrier();
        SB();
        MFMA_PART(1, av0, bv1, 0, 1);
        SB();
        STAGE_A(1, t2, cur);
        SB();
        MFMA_PART(1, av0, bv1, 1, 4);
        SB();
        // ---- P2: Q2 (av1 x bv1) | av0 <- np.A0(t+1) | stage A0(t+2)->cur
        asm volatile("s_waitcnt vmcnt(6)");   // drains {B1,A1,A0}(t+1)
        __builtin_amdgcn_s_barrier();
        SB();
        MFMA_PART(2, av1, bv1, 0, 1);
        SB();
        LOAD_A(av0, np);
        STAGE_A(0, t2, cur);
        SB();
        MFMA_PART(2, av1, bv1, 1, 4);
        SB();
        // ---- P3: Q3 (av1 x bv0) | bv1 <- np.B1(t+1) | stage B0(t+2)->cur
        asm volatile("s_waitcnt vmcnt(6)");   // drains {B0}(t+1)
        __builtin_amdgcn_s_barrier();
        SB();
        MFMA_PART(3, av1, bv0, 0, 1);
        SB();
        LOAD_B(bv1, np + 16384);
        STAGE_B(0, t2, cur);
        SB();
        MFMA_PART(3, av1, bv0, 1, 4);
        SB();
        LOAD_B(bv0, np);     // bv0 regs freed by Q3; B0(t+1) landed (P3-top wait)
        par ^= 1;
    }

    // ---- epilogue: drain tail DMAs before reusing LDS as scratch.
    asm volatile("s_waitcnt vmcnt(0)");
    __builtin_amdgcn_s_barrier();

    // Per-wave private scratch (2560 B), padded stride 36 floats -> float4
    // reads conflict-free. No cross-wave sharing => no barriers, only
    // intra-wave compiler fences (HW orders same-wave LDS ops).
    float* scratch = (float*)(void*)smem + w * 640;
    const int jj   = lane & 7;
    const int rsel = lane >> 3;

    // Hoisted epilogue prefetch: cell + bias (operand regs dead here).
    float  cpre[4][4][2];
    float4 gi4[4];
#pragma unroll
    for (int qd = 0; qd < 4; ++qd) {
        const int qa = (qd >= 2) ? 1 : 0;
        const int qb = (qd == 1 || qd == 2) ? 1 : 0;
        const int rowbase = m0 + qa * 128 + wr * 64;
        const int jg = j0 + qb * 32 + wc * 8 + jj;
        gi4[qd] = *(const float4*)(ginit + (size_t)jg * 4);
#pragma unroll
        for (int fi = 0; fi < 4; ++fi)
#pragma unroll
            for (int p = 0; p < 2; ++p)
                cpre[qd][fi][p] = cell[(size_t)(rowbase + fi * 16 + rsel + p * 8) * HID + jg];
    }

#pragma unroll
    for (int qd = 0; qd < 4; ++qd) {
        const int qa = (qd >= 2) ? 1 : 0;
        const int qb = (qd == 1 || qd == 2) ? 1 : 0;
        const int rowbase = m0 + qa * 128 + wr * 64;
        const int jg = j0 + qb * 32 + wc * 8 + jj;
        const float4 gi = gi4[qd];
#pragma unroll
        for (int fi = 0; fi < 4; ++fi) {
            // 16x32 slab: C/D frag layout col=lane&15, row=ql*4+reg
#pragma unroll
            for (int fj = 0; fj < 2; ++fj)
#pragma unroll
                for (int r = 0; r < 4; ++r)
                    scratch[(ql * 4 + r) * 36 + fj * 16 + lr] = acc[qd][fi][fj][r];
            asm volatile("" ::: "memory");
#pragma unroll
            for (int p = 0; p < 2; ++p) {
                const int row = rsel + p * 8;
                const float4 g = *(const float4*)(scratch + row * 36 + jj * 4);
                const int b = rowbase + fi * 16 + row;
                float iv = sigmf(g.x + gi.x);
                float fv = sigmf(g.y + gi.y);
                float gv = tanh_fast(g.z + gi.z);
                float ov = sigmf(g.w + gi.w);
                size_t ci = (size_t)b * HID + jg;
                float cn = fv * cpre[qd][fi][p] + iv * gv;
                cell[ci] = cn;
                float hv = ov * tanh_fast(cn);
                unsigned short hb = f2bf(hv);
                d1[(size_t)b * ld1 + off1 + jg] = hb;
                if (d2)  d2[(size_t)b * ld2 + off2 + jg] = hb;
                if (dfp) dfp[(size_t)b * HID + jg] = hv;
            }
            asm volatile("" ::: "memory");
        }
    }

    // ---- fused out phase (L1 only): y = h2 @ WoutT + bout for 16 own rows.
    if (wt) {
        // All waves' H2f stores drained to L2 by the syncthreads waitcnt;
        // release fetch_add emits buffer_wbl2 -> pushed to coherence point.
        __syncthreads();
        if (tid == 0) {
            __hip_atomic_fetch_add(&cnt[bx], 1u, __ATOMIC_RELEASE, __HIP_MEMORY_SCOPE_AGENT);
            // relaxed spin: agent-scope atomic loads read the coherence point
            while (__hip_atomic_load(&cnt[bx], __ATOMIC_RELAXED, __HIP_MEMORY_SCOPE_AGENT) < 16u)
                __builtin_amdgcn_s_sleep(2);
        }
        __syncthreads();

        // Stage our 16 H2f rows (rb..rb+15, all 1024 cols) into LDS.
        float* hl = (float*)(void*)smem;    // 64 KB
        const int rb = m0 + by * 16;
#pragma unroll
        for (int r = 0; r < 8; ++r) {
            int f4 = r * 512 + tid;
            *(float4*)(hl + f4 * 4) = *(const float4*)(dfp + (size_t)rb * 1024 + f4 * 4);
        }
        __syncthreads();
        const int o  = tid & 63;
        const int wv = tid >> 6;            // 0..7, 2 rows each
        float a0 = 0.f, a1 = 0.f;
#pragma unroll 8
        for (int k = 0; k < 1024; ++k) {
            float wvv = wt[k * 64 + o];
            const float* hr = hl + (wv * 2) * 1024 + k;
            a0 += hr[0]    * wvv;
            a1 += hr[1024] * wvv;
        }
        float bb = bo[o];
        int b = rb + wv * 2;
        float y0 = a0 + bb, y1 = a1 + bb;
        yout[(size_t)b * LDY + o] = y0;
        yout[(size_t)(b + 1) * LDY + o] = y1;
        xnY[(size_t)b * KA2 + 1152 + o] = f2bf(y0);
        xnY[(size_t)(b + 1) * KA2 + 1152 + o] = f2bf(y1);
    }
#undef MFMA_PART
#undef LOAD_A
#undef LOAD_B
#undef STAGE_A
#undef STAGE_B
}

// WoutT[k*64+o] = Wout[o*1024+k]
__global__ void build_woutT(const float* __restrict__ wout, float* __restrict__ wt)
{
    int idx = blockIdx.x * 256 + threadIdx.x;   // 65536
    int o = idx & 63, k = idx >> 6;
    wt[idx] = wout[(size_t)o * 1024 + k];
}

// interleaved bias: out[j*4+gate] = a[gate*1024+j] + b[gate*1024+j]
__global__ void build_bias(const float* __restrict__ a, const float* __restrict__ b,
                           float* __restrict__ o)
{
    int idx = blockIdx.x * 256 + threadIdx.x;   // 4096
    int gate = idx & 3, j = idx >> 2;
    int n = gate * 1024 + j;
    o[idx] = a[n] + b[n];
}

// W0[n] (KA2=1280): [0:128]=W_ih0[n][0:128] (static), [128:1152]=W_hh0[n][:],
// [1152:1216]=W_ih0[n][128:192] (y cols), [1216:1280]=0 (pad, never staged)
__global__ __launch_bounds__(256) void build_w0(
    const float* __restrict__ wih, const float* __restrict__ whh,
    unsigned short* __restrict__ w0)
{
    int idx = blockIdx.x * 256 + threadIdx.x;   // 4096*320 exact
    int n = idx / 320;
    int c = (idx - n * 320) * 4;
    float4 v = {0.f, 0.f, 0.f, 0.f};
    if (c < 128)       v = *(const float4*)(wih + (size_t)n * 192 + c);
    else if (c < 1152) v = *(const float4*)(whh + (size_t)n * 1024 + (c - 128));
    else if (c < 1216) v = *(const float4*)(wih + (size_t)n * 192 + 128 + (c - 1152));
    ushort4 o;
    o.x = f2bf(v.x); o.y = f2bf(v.y); o.z = f2bf(v.z); o.w = f2bf(v.w);
    *(ushort4*)(w0 + (size_t)n * KA2 + c) = o;
}

// W1[n][0:1024] = W_ih1[n][:], W1[n][1024:2048] = W_hh1[n][:]
__global__ __launch_bounds__(256) void build_w1(
    const float* __restrict__ wih, const float* __restrict__ whh,
    unsigned short* __restrict__ w1)
{
    int idx = blockIdx.x * 256 + threadIdx.x;   // 4096*512 exact
    int n = idx >> 9;
    int c = (idx & 511) * 4;
    float4 v;
    if (c < 1024) v = *(const float4*)(wih + (size_t)n * 1024 + c);
    else          v = *(const float4*)(whh + (size_t)n * 1024 + (c - 1024));
    ushort4 o;
    o.x = f2bf(v.x); o.y = f2bf(v.y); o.z = f2bf(v.z); o.w = f2bf(v.w);
    *(ushort4*)(w1 + (size_t)n * KB + c) = o;
}

// static bf16 into X0a and X0b cols 0..127
__global__ __launch_bounds__(256) void build_x0static(
    const float* __restrict__ stat, unsigned short* __restrict__ xa,
    unsigned short* __restrict__ xb)
{
    int idx = blockIdx.x * 256 + threadIdx.x;   // 4096*32 exact
    int b = idx >> 5;
    int c = (idx & 31) * 4;
    float4 v = *(const float4*)(stat + (size_t)b * 128 + c);
    ushort4 o;
    o.x = f2bf(v.x); o.y = f2bf(v.y); o.z = f2bf(v.z); o.w = f2bf(v.w);
    *(ushort4*)(xa + (size_t)b * KA2 + c) = o;
    *(ushort4*)(xb + (size_t)b * KA2 + c) = o;
}

extern "C" void kernel_launch(void* const* d_in, const int* in_sizes, int n_in,
                              void* d_out, int out_size, void* d_ws, size_t ws_size,
                              hipStream_t stream)
{
    (void)in_sizes; (void)n_in; (void)out_size; (void)ws_size;
    const float* static_in = (const float*)d_in[0];
    const float* Wih0 = (const float*)d_in[1];
    const float* Whh0 = (const float*)d_in[2];
    const float* bih0 = (const float*)d_in[3];
    const float* bhh0 = (const float*)d_in[4];
    const float* Wih1 = (const float*)d_in[5];
    const float* Whh1 = (const float*)d_in[6];
    const float* bih1 = (const float*)d_in[7];
    const float* bhh1 = (const float*)d_in[8];
    const float* Wout = (const float*)d_in[9];
    const float* bout = (const float*)d_in[10];
    float* out = (float*)d_out;

    char* p = (char*)d_ws;
    size_t off = 0;
    auto take = [&](size_t n) { char* r = p + off; off += (n + 255) & ~(size_t)255; return r; };

    unsigned short* W0   = (unsigned short*)take((size_t)4096 * KA2 * 2);
    unsigned short* W1   = (unsigned short*)take((size_t)4096 * KB * 2);
    float*          B1b  = (float*)take(4096 * 4);
    float*          B0b  = (float*)take(4096 * 4);
    float*          WoT  = (float*)take((size_t)1024 * 64 * 4);
    float*          H2f  = (float*)take((size_t)BATCH * HID * 4);
    float*          C1   = (float*)take((size_t)BATCH * HID * 4);
    float*          C2   = (float*)take((size_t)BATCH * HID * 4);
    unsigned short* X0a  = (unsigned short*)take((size_t)BATCH * KA2 * 2);
    unsigned short* X0b  = (unsigned short*)take((size_t)BATCH * KA2 * 2);
    unsigned short* X1a  = (unsigned short*)take((size_t)BATCH * KB * 2);
    unsigned short* X1b  = (unsigned short*)take((size_t)BATCH * KB * 2);
    unsigned*       cnt  = (unsigned*)take(TSTEPS * 16 * 4);
    // total ~131 MiB

    hipMemsetAsync(C1, 0, (size_t)BATCH * HID * 4, stream);
    hipMemsetAsync(C2, 0, (size_t)BATCH * HID * 4, stream);
    hipMemsetAsync(X0a, 0, (size_t)BATCH * KA2 * 2, stream);  // y0 = h1_0 = 0, pad = 0
    hipMemsetAsync(X0b, 0, (size_t)BATCH * KA2 * 2, stream);
    hipMemsetAsync(X1a, 0, (size_t)BATCH * KB * 2, stream);   // h2_0 = 0
    hipMemsetAsync(cnt, 0, TSTEPS * 16 * 4, stream);          // re-zero every run

    build_w0<<<5120, 256, 0, stream>>>(Wih0, Whh0, W0);
    build_w1<<<8192, 256, 0, stream>>>(Wih1, Whh1, W1);
    build_woutT<<<256, 256, 0, stream>>>(Wout, WoT);
    build_bias<<<16, 256, 0, stream>>>(bih0, bhh0, B0b);
    build_bias<<<16, 256, 0, stream>>>(bih1, bhh1, B1b);
    build_x0static<<<512, 256, 0, stream>>>(static_in, X0a, X0b);

    dim3 grid(16, 16);   // 256 blocks of 512 thr = 1 per CU (128 KB LDS)
    for (int t = 0; t < TSTEPS; ++t) {
        unsigned short* X0c = (t & 1) ? X0b : X0a;
        unsigned short* X0n = (t & 1) ? X0a : X0b;
        unsigned short* X1c = (t & 1) ? X1b : X1a;
        unsigned short* X1n = (t & 1) ? X1a : X1b;
        // layer 0: gates = X0c @ W0^T + b0; h1 -> X1c[:,0:1024] and X0n[:,128:1152]
        lstm_gate_gemm<<<grid, 512, 0, stream>>>(X0c, KA2, KT0, W0, B0b, C1,
                                                 X1c, KB, 0, X0n, KA2, 128, nullptr,
                                                 nullptr, nullptr, nullptr, nullptr, nullptr);
        // layer 1: gates = X1c @ W1^T + b1; h2 -> X1n[:,1024:2048] + H2f;
        // fused out phase: y_t -> out[:,t,:] and X0n[:,1152:1216]
        lstm_gate_gemm<<<grid, 512, 0, stream>>>(X1c, KB, KB, W1, B1b, C2,
                                                 X1n, KB, 1024, nullptr, 0, 0, H2f,
                                                 WoT, bout, out + t * NOUT, X0n,
                                                 cnt + t * 16);
    }
}